// Round 5
// baseline (150.880 us; speedup 1.0000x reference)
//
#include <hip/hip_runtime.h>

// B=64, D=2048, UNITS=1024, NW=64; L = in_sizes[3]/(UNITS*NW) (~56).
//
// out[b,u] = sum_i x[b,i] * W[u,i] + bias[u], W[u,i] = w[k] where bucket k of
// unit u contains position i (indices 1-shifted, 0 = pad). Buckets partition
// positions per unit -> LDS scatter builds W[u,:] race-free.
//
// R5 vs R4 post-mortem: kernel ~27us, still latency-bound (harness poison
// fills evict all of L3 each replay -> HBM-cold inputs, ~900cyc loads).
// R5: (a) 512 blocks x 512 thr, U=2 -> 2 blocks/CU so one block computes
// while the other drains its scatter barrier; (b) step-0 x prefetch issued
// BEFORE the barrier (x loads don't depend on the scatter); (c) double-
// buffered step loop (unroll 2) keeps next step's 8 x-loads in flight during
// FMAs. Live set ~110 VGPR < 128 cap (4 waves/SIMD) -- no spill (R2 tripwire).

#define B_DIM   64
#define D_DIM   2048
#define D4      (D_DIM / 4)     // 512 float4 per row
#define UNITS_N 1024
#define NW_N    64
#define U_PER_BLOCK 2
#define THREADS 512
#define WAVES   (THREADS / 64)          // 8
#define PAIRS_PER_WAVE (U_PER_BLOCK * NW_N / WAVES)   // 16
#define ROWS_PER_WAVE  (B_DIM / WAVES)  // 8
#define STEPS   (D4 / 64)               // 8

__global__ __launch_bounds__(THREADS, 4)
void EfficientHashedLinear_72043781423546_kernel(
    const float* __restrict__ x,        // (64, 2048)
    const float* __restrict__ w,        // (64,)
    const float* __restrict__ bias,     // (1024,)
    const int*   __restrict__ indices,  // (UNITS, NW, L) int32
    float*       __restrict__ out,      // (64, 1024)
    int L)
{
    __shared__ float rows[U_PER_BLOCK][D_DIM];   // 16 KB
    __shared__ float w_lds[NW_N];

    const int tid  = threadIdx.x;
    const int wave = tid >> 6;          // 0..7
    const int lane = tid & 63;
    const int u0   = blockIdx.x * U_PER_BLOCK;

    // Phase 0: zero rows (float4), stage w.
    {
        float4* r4 = (float4*)rows;
        const float4 z = make_float4(0.f, 0.f, 0.f, 0.f);
        #pragma unroll
        for (int i = tid; i < U_PER_BLOCK * D4; i += THREADS)
            r4[i] = z;
        if (tid < NW_N) w_lds[tid] = w[tid];
    }

    // Phase 1a: index load pass — 16 independent lane-predicated loads/wave,
    // all in flight before any use.
    int idxv[PAIRS_PER_WAVE];
    #pragma unroll
    for (int p = 0; p < PAIRS_PER_WAVE; ++p) {
        const int pair = wave * PAIRS_PER_WAVE + p;   // 0..127
        const int uu   = pair >> 6;                   // 0..1
        const int k    = pair & 63;                   // 0..63
        const int* bp  = indices + ((size_t)(u0 + uu) * NW_N + k) * L;
        idxv[p] = (lane < L) ? bp[lane] : 0;
    }

    // Phase 2 prefetch (step 0): x loads are independent of the scatter, so
    // issue them now — their HBM latency hides behind the barrier drain.
    const int b0 = wave * ROWS_PER_WAVE;
    const float4* x4 = (const float4*)x;
    float4 xc[ROWS_PER_WAVE];
    #pragma unroll
    for (int bj = 0; bj < ROWS_PER_WAVE; ++bj)
        xc[bj] = x4[(b0 + bj) * D4 + lane];

    __syncthreads();   // rows[] zeroed before scatter

    // Phase 1b: scatter pass (LDS only).
    #pragma unroll
    for (int p = 0; p < PAIRS_PER_WAVE; ++p) {
        const int pair = wave * PAIRS_PER_WAVE + p;
        const int uu   = pair >> 6;
        const int k    = pair & 63;
        if (idxv[p] > 0) rows[uu][idxv[p] - 1] = w_lds[k];
    }
    // Generic tail for L > 64 (not expected with this data; kept for safety).
    if (L > 64) {
        #pragma unroll 1
        for (int p = 0; p < PAIRS_PER_WAVE; ++p) {
            const int pair = wave * PAIRS_PER_WAVE + p;
            const int uu   = pair >> 6;
            const int k    = pair & 63;
            const int* bp  = indices + ((size_t)(u0 + uu) * NW_N + k) * L;
            const float wk = w_lds[k];
            for (int l = 64 + lane; l < L; l += 64) {
                int idx = bp[l];
                if (idx > 0) rows[uu][idx - 1] = wk;
            }
        }
    }
    __syncthreads();

    // Phase 2: each wave owns 8 batch rows x 2 units; lanes split D as float4.
    // Double-buffered: next step's x loads are in flight during FMAs.
    float acc[ROWS_PER_WAVE][U_PER_BLOCK];
    #pragma unroll
    for (int bj = 0; bj < ROWS_PER_WAVE; ++bj)
        #pragma unroll
        for (int uu = 0; uu < U_PER_BLOCK; ++uu)
            acc[bj][uu] = 0.0f;

    #pragma unroll 2   // even/odd buffer rotation; live ~110 VGPR
    for (int step = 0; step < STEPS; ++step) {
        const int i4 = step * 64 + lane;
        float4 xn[ROWS_PER_WAVE];
        if (step + 1 < STEPS) {
            #pragma unroll
            for (int bj = 0; bj < ROWS_PER_WAVE; ++bj)
                xn[bj] = x4[(b0 + bj) * D4 + (i4 + 64)];
        }
        float4 rv[U_PER_BLOCK];
        #pragma unroll
        for (int uu = 0; uu < U_PER_BLOCK; ++uu)
            rv[uu] = ((const float4*)rows[uu])[i4];   // ds_read_b128
        #pragma unroll
        for (int bj = 0; bj < ROWS_PER_WAVE; ++bj) {
            #pragma unroll
            for (int uu = 0; uu < U_PER_BLOCK; ++uu) {
                acc[bj][uu] += xc[bj].x * rv[uu].x;
                acc[bj][uu] += xc[bj].y * rv[uu].y;
                acc[bj][uu] += xc[bj].z * rv[uu].z;
                acc[bj][uu] += xc[bj].w * rv[uu].w;
            }
        }
        if (step + 1 < STEPS) {
            #pragma unroll
            for (int bj = 0; bj < ROWS_PER_WAVE; ++bj)
                xc[bj] = xn[bj];
        }
    }

    // Phase 3: butterfly reduce, add bias, store (16 outputs/wave).
    #pragma unroll
    for (int bj = 0; bj < ROWS_PER_WAVE; ++bj) {
        #pragma unroll
        for (int uu = 0; uu < U_PER_BLOCK; ++uu) {
            float v = acc[bj][uu];
            #pragma unroll
            for (int off = 32; off > 0; off >>= 1)
                v += __shfl_down(v, off, 64);
            if (lane == 0)
                out[(b0 + bj) * UNITS_N + (u0 + uu)] = v + bias[u0 + uu];
        }
    }
}

extern "C" void kernel_launch(void* const* d_in, const int* in_sizes, int n_in,
                              void* d_out, int out_size, void* d_ws, size_t ws_size,
                              hipStream_t stream) {
    const float* x       = (const float*)d_in[0];
    const float* w       = (const float*)d_in[1];
    const float* bias    = (const float*)d_in[2];
    const int*   indices = (const int*)d_in[3];
    float*       out     = (float*)d_out;

    const int L = in_sizes[3] / (UNITS_N * NW_N);

    dim3 grid(UNITS_N / U_PER_BLOCK);   // 512 blocks = 2 per CU
    dim3 block(THREADS);                // 512 threads = 8 waves
    EfficientHashedLinear_72043781423546_kernel<<<grid, block, 0, stream>>>(
        x, w, bias, indices, out, L);
}

// Round 6
// 91.255 us; speedup vs baseline: 1.6534x; 1.6534x over previous
//
#include <hip/hip_runtime.h>

// B=64, D=2048, UNITS=1024, NW=64; L = in_sizes[3]/(UNITS*NW) (~56).
//
// out[b,u] = sum_i x[b,i] * W[u,i] + bias[u], W[u,i] = w[k] where bucket k of
// unit u contains position i (indices 1-shifted, 0 = pad). Buckets partition
// positions per unit -> LDS scatter builds W[u,:] race-free.
//
// R6 vs R5 post-mortem: R5's __launch_bounds__(512,4) capped the allocator
// at 64 VGPR (2nd arg behaves like a blocks/CU bound here: 4x8 waves ->
// 8 waves/SIMD -> 64 cap) and the ~100-reg prefetch live set spilled 161 MB
// of scratch (WRITE_SIZE counter). R6: identical structure, NO second
// launch_bounds arg. Expect VGPR ~104-128 -> 4 waves/SIMD -> 2 blocks/CU
// co-resident (cross-block barrier overlap), WRITE_SIZE back to ~512 KB.

#define B_DIM   64
#define D_DIM   2048
#define D4      (D_DIM / 4)     // 512 float4 per row
#define UNITS_N 1024
#define NW_N    64
#define U_PER_BLOCK 2
#define THREADS 512
#define WAVES   (THREADS / 64)          // 8
#define PAIRS_PER_WAVE (U_PER_BLOCK * NW_N / WAVES)   // 16
#define ROWS_PER_WAVE  (B_DIM / WAVES)  // 8
#define STEPS   (D4 / 64)               // 8

__global__ __launch_bounds__(THREADS)   // no 2nd arg: it caps VGPR at 64 here
void EfficientHashedLinear_72043781423546_kernel(
    const float* __restrict__ x,        // (64, 2048)
    const float* __restrict__ w,        // (64,)
    const float* __restrict__ bias,     // (1024,)
    const int*   __restrict__ indices,  // (UNITS, NW, L) int32
    float*       __restrict__ out,      // (64, 1024)
    int L)
{
    __shared__ float rows[U_PER_BLOCK][D_DIM];   // 16 KB
    __shared__ float w_lds[NW_N];

    const int tid  = threadIdx.x;
    const int wave = tid >> 6;          // 0..7
    const int lane = tid & 63;
    const int u0   = blockIdx.x * U_PER_BLOCK;

    // Phase 0: zero rows (float4), stage w.
    {
        float4* r4 = (float4*)rows;
        const float4 z = make_float4(0.f, 0.f, 0.f, 0.f);
        #pragma unroll
        for (int i = tid; i < U_PER_BLOCK * D4; i += THREADS)
            r4[i] = z;
        if (tid < NW_N) w_lds[tid] = w[tid];
    }

    // Phase 1a: index load pass — 16 independent lane-predicated loads/wave,
    // all in flight before any use.
    int idxv[PAIRS_PER_WAVE];
    #pragma unroll
    for (int p = 0; p < PAIRS_PER_WAVE; ++p) {
        const int pair = wave * PAIRS_PER_WAVE + p;   // 0..127
        const int uu   = pair >> 6;                   // 0..1
        const int k    = pair & 63;                   // 0..63
        const int* bp  = indices + ((size_t)(u0 + uu) * NW_N + k) * L;
        idxv[p] = (lane < L) ? bp[lane] : 0;
    }

    // Step-0 x prefetch: independent of the scatter, so issue before the
    // barrier — its HBM latency hides behind the barrier drain.
    const int b0 = wave * ROWS_PER_WAVE;
    const float4* x4 = (const float4*)x;
    float4 xc[ROWS_PER_WAVE];
    #pragma unroll
    for (int bj = 0; bj < ROWS_PER_WAVE; ++bj)
        xc[bj] = x4[(b0 + bj) * D4 + lane];

    __syncthreads();   // rows[] zeroed before scatter

    // Phase 1b: scatter pass (LDS only).
    #pragma unroll
    for (int p = 0; p < PAIRS_PER_WAVE; ++p) {
        const int pair = wave * PAIRS_PER_WAVE + p;
        const int uu   = pair >> 6;
        const int k    = pair & 63;
        if (idxv[p] > 0) rows[uu][idxv[p] - 1] = w_lds[k];
    }
    // Generic tail for L > 64 (not expected with this data; kept for safety).
    if (L > 64) {
        #pragma unroll 1
        for (int p = 0; p < PAIRS_PER_WAVE; ++p) {
            const int pair = wave * PAIRS_PER_WAVE + p;
            const int uu   = pair >> 6;
            const int k    = pair & 63;
            const int* bp  = indices + ((size_t)(u0 + uu) * NW_N + k) * L;
            const float wk = w_lds[k];
            for (int l = 64 + lane; l < L; l += 64) {
                int idx = bp[l];
                if (idx > 0) rows[uu][idx - 1] = wk;
            }
        }
    }
    __syncthreads();

    // Phase 2: each wave owns 8 batch rows x 2 units; lanes split D as float4.
    // Double-buffered: next step's x loads are in flight during FMAs.
    float acc[ROWS_PER_WAVE][U_PER_BLOCK];
    #pragma unroll
    for (int bj = 0; bj < ROWS_PER_WAVE; ++bj)
        #pragma unroll
        for (int uu = 0; uu < U_PER_BLOCK; ++uu)
            acc[bj][uu] = 0.0f;

    #pragma unroll 2   // even/odd buffer rotation; live ~100 VGPR
    for (int step = 0; step < STEPS; ++step) {
        const int i4 = step * 64 + lane;
        float4 xn[ROWS_PER_WAVE];
        if (step + 1 < STEPS) {
            #pragma unroll
            for (int bj = 0; bj < ROWS_PER_WAVE; ++bj)
                xn[bj] = x4[(b0 + bj) * D4 + (i4 + 64)];
        }
        float4 rv[U_PER_BLOCK];
        #pragma unroll
        for (int uu = 0; uu < U_PER_BLOCK; ++uu)
            rv[uu] = ((const float4*)rows[uu])[i4];   // ds_read_b128
        #pragma unroll
        for (int bj = 0; bj < ROWS_PER_WAVE; ++bj) {
            #pragma unroll
            for (int uu = 0; uu < U_PER_BLOCK; ++uu) {
                acc[bj][uu] += xc[bj].x * rv[uu].x;
                acc[bj][uu] += xc[bj].y * rv[uu].y;
                acc[bj][uu] += xc[bj].z * rv[uu].z;
                acc[bj][uu] += xc[bj].w * rv[uu].w;
            }
        }
        if (step + 1 < STEPS) {
            #pragma unroll
            for (int bj = 0; bj < ROWS_PER_WAVE; ++bj)
                xc[bj] = xn[bj];
        }
    }

    // Phase 3: butterfly reduce, add bias, store (16 outputs/wave).
    #pragma unroll
    for (int bj = 0; bj < ROWS_PER_WAVE; ++bj) {
        #pragma unroll
        for (int uu = 0; uu < U_PER_BLOCK; ++uu) {
            float v = acc[bj][uu];
            #pragma unroll
            for (int off = 32; off > 0; off >>= 1)
                v += __shfl_down(v, off, 64);
            if (lane == 0)
                out[(b0 + bj) * UNITS_N + (u0 + uu)] = v + bias[u0 + uu];
        }
    }
}

extern "C" void kernel_launch(void* const* d_in, const int* in_sizes, int n_in,
                              void* d_out, int out_size, void* d_ws, size_t ws_size,
                              hipStream_t stream) {
    const float* x       = (const float*)d_in[0];
    const float* w       = (const float*)d_in[1];
    const float* bias    = (const float*)d_in[2];
    const int*   indices = (const int*)d_in[3];
    float*       out     = (float*)d_out;

    const int L = in_sizes[3] / (UNITS_N * NW_N);

    dim3 grid(UNITS_N / U_PER_BLOCK);   // 512 blocks = 2 per CU
    dim3 block(THREADS);                // 512 threads = 8 waves
    EfficientHashedLinear_72043781423546_kernel<<<grid, block, 0, stream>>>(
        x, w, bias, indices, out, L);
}

// Round 7
// 82.427 us; speedup vs baseline: 1.8305x; 1.1071x over previous
//
#include <hip/hip_runtime.h>

// B=64, D=2048, UNITS=1024, NW=64; L = in_sizes[3]/(UNITS*NW) (~56).
//
// out[b,u] = sum_i x[b,i] * W[u,i] + bias[u], W[u,i] = w[k] where bucket k of
// unit u contains position i (indices 1-shifted, 0 = pad). Buckets partition
// positions per unit -> LDS scatter builds W[u,:] race-free.
//
// R7 vs R6 post-mortem: R4 (256x1024thr, U=4, no prefetch) remains best
// (~26us kernel). Its flaw: grid 256 = 1 block/CU -> whole CU drains at each
// barrier (R3 profile: VALUBusy 9%, latency-bound). Every register-prefetch
// fix has hit the 64/128-VGPR allocator cliffs (R2/R5 spills, R6 occupancy
// loss). R7 gets overlap from BLOCK-level TLP instead: split batch in two ->
// grid (256,2) = 512 blocks x 512 thr, U=4, 32 rows/block, 4 rows/wave.
// Live set ~58 VGPR (R3-proven <=64), LDS 33 KB -> 4-blocks/CU capacity,
// 2 resident average: one block computes while another drains its barrier.
// Cost: indices read 2x (29 MB, ~+2us) -- cheap vs latency win.

#define B_DIM   64
#define D_DIM   2048
#define D4      (D_DIM / 4)     // 512 float4 per row
#define UNITS_N 1024
#define NW_N    64
#define U_PER_BLOCK 4
#define B_PER_BLOCK 32
#define THREADS 512
#define WAVES   (THREADS / 64)                      // 8
#define PAIRS_PER_WAVE (U_PER_BLOCK * NW_N / WAVES) // 32
#define ROWS_PER_WAVE  (B_PER_BLOCK / WAVES)        // 4
#define STEPS   (D4 / 64)                           // 8

__global__ __launch_bounds__(THREADS)   // NO 2nd arg: it triggers 64-VGPR cap + spill (R5)
void EfficientHashedLinear_72043781423546_kernel(
    const float* __restrict__ x,        // (64, 2048)
    const float* __restrict__ w,        // (64,)
    const float* __restrict__ bias,     // (1024,)
    const int*   __restrict__ indices,  // (UNITS, NW, L) int32
    float*       __restrict__ out,      // (64, 1024)
    int L)
{
    __shared__ float rows[U_PER_BLOCK][D_DIM];   // 32 KB
    __shared__ float w_lds[NW_N];

    const int tid  = threadIdx.x;
    const int wave = tid >> 6;          // 0..7
    const int lane = tid & 63;
    const int u0   = blockIdx.x * U_PER_BLOCK;
    const int bh   = blockIdx.y;        // batch half: 0 or 1

    // Phase 0: zero rows (float4), stage w.
    {
        float4* r4 = (float4*)rows;
        const float4 z = make_float4(0.f, 0.f, 0.f, 0.f);
        #pragma unroll
        for (int i = tid; i < U_PER_BLOCK * D4; i += THREADS)
            r4[i] = z;
        if (tid < NW_N) w_lds[tid] = w[tid];
    }

    // Phase 1a: index load pass — 32 independent lane-predicated loads/wave,
    // all issued before any use (R4's batching, proven vs R3's serial loop).
    int idxv[PAIRS_PER_WAVE];
    #pragma unroll
    for (int p = 0; p < PAIRS_PER_WAVE; ++p) {
        const int pair = wave * PAIRS_PER_WAVE + p;   // 0..255
        const int uu   = pair >> 6;                   // 0..3
        const int k    = pair & 63;                   // 0..63
        const int* bp  = indices + ((size_t)(u0 + uu) * NW_N + k) * L;
        idxv[p] = (lane < L) ? bp[lane] : 0;
    }

    __syncthreads();   // rows[] zeroed before scatter

    // Phase 1b: scatter pass (LDS only).
    #pragma unroll
    for (int p = 0; p < PAIRS_PER_WAVE; ++p) {
        const int pair = wave * PAIRS_PER_WAVE + p;
        const int uu   = pair >> 6;
        const int k    = pair & 63;
        if (idxv[p] > 0) rows[uu][idxv[p] - 1] = w_lds[k];
    }
    // Generic tail for L > 64 (not expected with this data; kept for safety).
    if (L > 64) {
        #pragma unroll 1
        for (int p = 0; p < PAIRS_PER_WAVE; ++p) {
            const int pair = wave * PAIRS_PER_WAVE + p;
            const int uu   = pair >> 6;
            const int k    = pair & 63;
            const int* bp  = indices + ((size_t)(u0 + uu) * NW_N + k) * L;
            const float wk = w_lds[k];
            for (int l = 64 + lane; l < L; l += 64) {
                int idx = bp[l];
                if (idx > 0) rows[uu][idx - 1] = wk;
            }
        }
    }
    __syncthreads();

    // Phase 2: wave owns 4 batch rows (of this block's 32) x 4 units.
    const int b0 = bh * B_PER_BLOCK + wave * ROWS_PER_WAVE;
    const float4* x4 = (const float4*)x;

    float acc[ROWS_PER_WAVE][U_PER_BLOCK];
    #pragma unroll
    for (int bj = 0; bj < ROWS_PER_WAVE; ++bj)
        #pragma unroll
        for (int uu = 0; uu < U_PER_BLOCK; ++uu)
            acc[bj][uu] = 0.0f;

    #pragma unroll 1   // live set ~58 VGPR; bigger unrolls hit the 64 cliff
    for (int step = 0; step < STEPS; ++step) {
        const int i4 = step * 64 + lane;          // 0..511
        float4 rv[U_PER_BLOCK];
        #pragma unroll
        for (int uu = 0; uu < U_PER_BLOCK; ++uu)
            rv[uu] = ((const float4*)rows[uu])[i4];   // ds_read_b128
        #pragma unroll
        for (int bj = 0; bj < ROWS_PER_WAVE; ++bj) {
            const float4 xv = x4[(b0 + bj) * D4 + i4];
            #pragma unroll
            for (int uu = 0; uu < U_PER_BLOCK; ++uu) {
                acc[bj][uu] += xv.x * rv[uu].x;
                acc[bj][uu] += xv.y * rv[uu].y;
                acc[bj][uu] += xv.z * rv[uu].z;
                acc[bj][uu] += xv.w * rv[uu].w;
            }
        }
    }

    // Phase 3: butterfly reduce, add bias, store (16 outputs/wave).
    #pragma unroll
    for (int bj = 0; bj < ROWS_PER_WAVE; ++bj) {
        #pragma unroll
        for (int uu = 0; uu < U_PER_BLOCK; ++uu) {
            float v = acc[bj][uu];
            #pragma unroll
            for (int off = 32; off > 0; off >>= 1)
                v += __shfl_down(v, off, 64);
            if (lane == 0)
                out[(b0 + bj) * UNITS_N + (u0 + uu)] = v + bias[u0 + uu];
        }
    }
}

extern "C" void kernel_launch(void* const* d_in, const int* in_sizes, int n_in,
                              void* d_out, int out_size, void* d_ws, size_t ws_size,
                              hipStream_t stream) {
    const float* x       = (const float*)d_in[0];
    const float* w       = (const float*)d_in[1];
    const float* bias    = (const float*)d_in[2];
    const int*   indices = (const int*)d_in[3];
    float*       out     = (float*)d_out;

    const int L = in_sizes[3] / (UNITS_N * NW_N);

    dim3 grid(UNITS_N / U_PER_BLOCK, 2);   // (256, 2) = 512 blocks, ~2/CU
    dim3 block(THREADS);                   // 512 threads = 8 waves
    EfficientHashedLinear_72043781423546_kernel<<<grid, block, 0, stream>>>(
        x, w, bias, indices, out, L);
}